// Round 3
// baseline (2517.828 us; speedup 1.0000x reference)
//
#include <hip/hip_runtime.h>
#include <math.h>

typedef short bf16x8 __attribute__((ext_vector_type(8)));
typedef float f32x4 __attribute__((ext_vector_type(4)));
typedef unsigned int u32;

__device__ __forceinline__ ushort f2bf(float f) {
    unsigned u = __float_as_uint(f);
    u = u + 0x7FFFu + ((u >> 16) & 1u);
    return (ushort)(u >> 16);
}
__device__ __forceinline__ float bf2f(ushort h) {
    return __uint_as_float(((unsigned)h) << 16);
}

// async global->LDS, 16B per lane; lds base must be wave-uniform (dst = base + lane*16)
__device__ __forceinline__ void async16(const void* g, void* l) {
    __builtin_amdgcn_global_load_lds((const __attribute__((address_space(1))) u32*)g,
                                     (__attribute__((address_space(3))) u32*)l, 16, 0, 0);
}

#define LSTRIDE 40   // ew_kernel LDS row stride in bf16 elements (32 data + 8 pad)

// ---------------------------------------------------------------------------
// Stage 1: EWt = (embed[0:8150,0:300] @ W[0:300,0:512])^T as bf16 hi/lo,
// shape [512][8192]. Split-bf16 (hh+hl+lh). grid (64,4), 512 threads.
// ---------------------------------------------------------------------------
__global__ __launch_bounds__(512, 4) void ew_kernel(
    const float* __restrict__ embed, const float* __restrict__ W,
    ushort* __restrict__ EWt_hi, ushort* __restrict__ EWt_lo) {
    __shared__ ushort Ah[128 * LSTRIDE], Al[128 * LSTRIDE];
    __shared__ ushort Bh[128 * LSTRIDE], Bl[128 * LSTRIDE];
    int bm = blockIdx.x * 128;
    int bn = blockIdx.y * 128;
    int tid = threadIdx.x;
    int lane = tid & 63, w = tid >> 6;
    int quad = lane >> 4, l16 = lane & 15;
    int wm = (w & 3) * 32, wn = (w >> 2) * 64;

    f32x4 acc[2][4];
#pragma unroll
    for (int a = 0; a < 2; a++)
#pragma unroll
        for (int b = 0; b < 4; b++) acc[a][b] = (f32x4){0.f, 0.f, 0.f, 0.f};

    for (int k0 = 0; k0 < 320; k0 += 32) {
#pragma unroll
        for (int r = 0; r < 2; r++) {
            int flat = tid + r * 512;
            int m = flat >> 3, kk4 = (flat & 7) * 4;
            int gm = bm + m, gk = k0 + kk4;
            float4 v = make_float4(0.f, 0.f, 0.f, 0.f);
            if (gm < 8150 && gk < 300) v = *(const float4*)&embed[(size_t)gm * 300 + gk];
            ushort4 h, l;
            h.x = f2bf(v.x); l.x = f2bf(v.x - bf2f(h.x));
            h.y = f2bf(v.y); l.y = f2bf(v.y - bf2f(h.y));
            h.z = f2bf(v.z); l.z = f2bf(v.z - bf2f(h.z));
            h.w = f2bf(v.w); l.w = f2bf(v.w - bf2f(h.w));
            *(ushort4*)&Ah[m * LSTRIDE + kk4] = h;
            *(ushort4*)&Al[m * LSTRIDE + kk4] = l;
        }
#pragma unroll
        for (int p = 0; p < 8; p++) {
            int kk = (tid >> 7) + p * 4;
            int n = tid & 127;
            int gk = k0 + kk;
            float v = (gk < 300) ? W[(size_t)gk * 512 + bn + n] : 0.f;
            ushort h = f2bf(v);
            Bh[n * LSTRIDE + kk] = h;
            Bl[n * LSTRIDE + kk] = f2bf(v - bf2f(h));
        }
        __syncthreads();
        bf16x8 a_h[2], a_l[2];
#pragma unroll
        for (int mf = 0; mf < 2; mf++) {
            int row = wm + mf * 16 + l16;
            a_h[mf] = *(const bf16x8*)&Ah[row * LSTRIDE + quad * 8];
            a_l[mf] = *(const bf16x8*)&Al[row * LSTRIDE + quad * 8];
        }
#pragma unroll
        for (int nf = 0; nf < 4; nf++) {
            int col = wn + nf * 16 + l16;
            bf16x8 b_h = *(const bf16x8*)&Bh[col * LSTRIDE + quad * 8];
            bf16x8 b_l = *(const bf16x8*)&Bl[col * LSTRIDE + quad * 8];
#pragma unroll
            for (int mf = 0; mf < 2; mf++) {
                acc[mf][nf] = __builtin_amdgcn_mfma_f32_16x16x32_bf16(a_h[mf], b_h, acc[mf][nf], 0, 0, 0);
                acc[mf][nf] = __builtin_amdgcn_mfma_f32_16x16x32_bf16(a_h[mf], b_l, acc[mf][nf], 0, 0, 0);
                acc[mf][nf] = __builtin_amdgcn_mfma_f32_16x16x32_bf16(a_l[mf], b_h, acc[mf][nf], 0, 0, 0);
            }
        }
        __syncthreads();
    }
#pragma unroll
    for (int mf = 0; mf < 2; mf++)
#pragma unroll
        for (int nf = 0; nf < 4; nf++) {
            int gn = bn + wn + nf * 16 + l16;
            int gm = bm + wm + mf * 16 + quad * 4;
            ushort4 h4, l4;
            float v0 = acc[mf][nf][0], v1 = acc[mf][nf][1];
            float v2 = acc[mf][nf][2], v3 = acc[mf][nf][3];
            h4.x = f2bf(v0); l4.x = f2bf(v0 - bf2f(h4.x));
            h4.y = f2bf(v1); l4.y = f2bf(v1 - bf2f(h4.y));
            h4.z = f2bf(v2); l4.z = f2bf(v2 - bf2f(h4.z));
            h4.w = f2bf(v3); l4.w = f2bf(v3 - bf2f(h4.w));
            *(ushort4*)&EWt_hi[(size_t)gn * 8192 + gm] = h4;
            *(ushort4*)&EWt_lo[(size_t)gn * 8192 + gm] = l4;
        }
}

// ---------------------------------------------------------------------------
// Stage 2 V2: Zx += X @ EW. A: global->register fp32->bf16 hi/lo (fused).
// B: EWt bf16 via global_load_lds into unpadded [n][32] LDS.
// 128x256 tile, 4 waves of 64x128, splitK=8, rotated atomicAdd epilogue.
// ---------------------------------------------------------------------------
__global__ __launch_bounds__(256, 2) void zx_kernel(
    const float* __restrict__ X, const ushort* __restrict__ EWt_hi,
    const ushort* __restrict__ EWt_lo, float* __restrict__ Zx) {
    __shared__ ushort Bh[256 * 32];
    __shared__ ushort Bl[256 * 32];
    int bm = blockIdx.x * 128;          // 46
    int bn = blockIdx.y * 256;          // 2
    int kc = blockIdx.z * 1024;         // 8
    int tid = threadIdx.x;
    int w = tid >> 6, lane = tid & 63;
    int quad = lane >> 4, l16 = lane & 15;
    int wm = (w & 1) * 64, wn = (w >> 1) * 128;
    int dn_row = lane >> 2;             // DMA: row within 16-row group
    int dk_off = (lane & 3) * 8;        // DMA: k offset (8 bf16 = 16B)

    f32x4 acc[4][8];
#pragma unroll
    for (int a = 0; a < 4; a++)
#pragma unroll
        for (int b = 0; b < 8; b++) acc[a][b] = (f32x4){0.f, 0.f, 0.f, 0.f};

    for (int step = 0; step < 32; step++) {
        int k0 = kc + step * 32;
        __syncthreads();   // previous iteration's LDS fully consumed
        // B staging via async DMA: each wave covers n-rows [w*64, w*64+64)
#pragma unroll
        for (int i = 0; i < 4; i++) {
            int nb = w * 64 + i * 16;
            size_t go = (size_t)(bn + nb + dn_row) * 8192 + k0 + dk_off;
            async16(&EWt_hi[go], &Bh[nb * 32]);
            async16(&EWt_lo[go], &Bl[nb * 32]);
        }
        // A: global->register, convert to bf16 hi/lo fragments
        bf16x8 a_h[4], a_l[4];
#pragma unroll
        for (int mf = 0; mf < 4; mf++) {
            int row = bm + wm + mf * 16 + l16;
            int gk = k0 + quad * 8;
            float v[8];
#pragma unroll
            for (int p = 0; p < 4; p++) {
                int kk = gk + p * 2;
                float2 t = make_float2(0.f, 0.f);
                if (kk + 1 < 8150) t = *(const float2*)&X[(size_t)row * 8150 + kk];
                v[p * 2] = t.x; v[p * 2 + 1] = t.y;
            }
            union { bf16x8 v8; ushort u[8]; } uh, ul;
#pragma unroll
            for (int p = 0; p < 8; p++) {
                ushort h = f2bf(v[p]);
                uh.u[p] = h;
                ul.u[p] = f2bf(v[p] - bf2f(h));
            }
            a_h[mf] = uh.v8; a_l[mf] = ul.v8;
        }
        __syncthreads();   // drains DMA (vmcnt(0) before barrier)
#pragma unroll
        for (int nf = 0; nf < 8; nf++) {
            int col = wn + nf * 16 + l16;
            bf16x8 b_h = *(const bf16x8*)&Bh[col * 32 + quad * 8];
            bf16x8 b_l = *(const bf16x8*)&Bl[col * 32 + quad * 8];
#pragma unroll
            for (int mf = 0; mf < 4; mf++) {
                acc[mf][nf] = __builtin_amdgcn_mfma_f32_16x16x32_bf16(a_h[mf], b_h, acc[mf][nf], 0, 0, 0);
                acc[mf][nf] = __builtin_amdgcn_mfma_f32_16x16x32_bf16(a_h[mf], b_l, acc[mf][nf], 0, 0, 0);
                acc[mf][nf] = __builtin_amdgcn_mfma_f32_16x16x32_bf16(a_l[mf], b_h, acc[mf][nf], 0, 0, 0);
            }
        }
    }
    int rot = blockIdx.z & 7;   // stagger atomic sweeps across splitK blocks
#pragma unroll
    for (int nfi = 0; nfi < 8; nfi++) {
        int nf = (nfi + rot) & 7;
        int col = bn + wn + nf * 16 + l16;
#pragma unroll
        for (int mf = 0; mf < 4; mf++) {
            int row = bm + wm + mf * 16 + quad * 4;
#pragma unroll
            for (int i = 0; i < 4; i++)
                atomicAdd(&Zx[(size_t)(row + i) * 512 + col], acc[mf][nf][i]);
        }
    }
}

// ---------------------------------------------------------------------------
// Wht prep: transpose W_lstm rows 300..427 into Wht[lstm][col 512][k 128]
// as bf16 hi/lo. grid 32 blocks x 256 threads.
// ---------------------------------------------------------------------------
__global__ void wht_prep(const float* __restrict__ W1, const float* __restrict__ W2,
                         ushort* __restrict__ Wht_hi, ushort* __restrict__ Wht_lo) {
    int lstm = blockIdx.x >> 4, cg = blockIdx.x & 15;
    const float* W = (lstm ? W2 : W1) + 300 * 512;
    ushort* oh = Wht_hi + (size_t)lstm * 512 * 128;
    ushort* ol = Wht_lo + (size_t)lstm * 512 * 128;
#pragma unroll
    for (int i = 0; i < 16; i++) {
        int idx = threadIdx.x + i * 256;
        int k = idx & 127, c = cg * 32 + (idx >> 7);
        float v = W[(size_t)k * 512 + c];
        ushort h = f2bf(v);
        oh[(size_t)c * 128 + k] = h;
        ol[(size_t)c * 128 + k] = f2bf(v - bf2f(h));
    }
}

#define TT 46

__device__ __forceinline__ float sigf(float x) { return 1.f / (1.f + expf(-x)); }

// ---------------------------------------------------------------------------
// LSTM V3: h@Wh via MFMA. h in LDS as bf16 hi/lo (16-row A fragment, rows 4..15
// zero). Wht streamed L2->registers as B fragments. 3-term split bf16.
// 64 blocks (2 lstm x 32 groups of 4 batch rows), 256 threads (4 waves x 128 cols).
// ---------------------------------------------------------------------------
__global__ __launch_bounds__(256) void lstm_kernel(
    const float* __restrict__ Zx1, const float* __restrict__ Zx2,
    const ushort* __restrict__ Wht_hi, const ushort* __restrict__ Wht_lo,
    const float* __restrict__ lng1, const float* __restrict__ lnb1,
    const float* __restrict__ lng2, const float* __restrict__ lnb2,
    float* __restrict__ o1, float* __restrict__ o2) {
    int lstm = blockIdx.x >> 5;
    int r0 = (blockIdx.x & 31) * 4;
    const float* Zx = lstm ? Zx2 : Zx1;
    const ushort* Wh = Wht_hi + (size_t)lstm * 512 * 128;
    const ushort* Wl = Wht_lo + (size_t)lstm * 512 * 128;
    const float* g  = lstm ? lng2 : lng1;
    const float* bb = lstm ? lnb2 : lnb1;
    float* obuf = lstm ? o2 : o1;

    __shared__ __align__(16) ushort hbh[16][128];  // h hi (rows 4..15 stay zero)
    __shared__ __align__(16) ushort hbl[16][128];  // h lo
    __shared__ __align__(16) float cs[4][128];
    __shared__ __align__(16) float zb[4][512];
    __shared__ float mu[4][4], rs[4][4], cmu[4], crs[4];

    int tid = threadIdx.x;
    int w = tid >> 6, lane = tid & 63;
    int quad = lane >> 4, l16 = lane & 15;
    int wn = w * 128;

    for (int i = tid; i < 16 * 128; i += 256) { hbh[0][i] = 0; hbl[0][i] = 0; }
    for (int i = tid; i < 512; i += 256) cs[i >> 7][i & 127] = 0.f;
    __syncthreads();

    for (int t = 0; t < TT; t++) {
        // ---- phase 1: z = h @ Wh via MFMA (rows 0..3 valid) ----
        f32x4 acc[8];
#pragma unroll
        for (int n = 0; n < 8; n++) acc[n] = (f32x4){0.f, 0.f, 0.f, 0.f};
#pragma unroll
        for (int ks = 0; ks < 4; ks++) {
            bf16x8 ah = *(const bf16x8*)&hbh[l16][ks * 32 + quad * 8];
            bf16x8 al = *(const bf16x8*)&hbl[l16][ks * 32 + quad * 8];
#pragma unroll
            for (int nf = 0; nf < 8; nf++) {
                int col = wn + nf * 16 + l16;
                bf16x8 bh = *(const bf16x8*)&Wh[(size_t)col * 128 + ks * 32 + quad * 8];
                bf16x8 bl = *(const bf16x8*)&Wl[(size_t)col * 128 + ks * 32 + quad * 8];
                acc[nf] = __builtin_amdgcn_mfma_f32_16x16x32_bf16(ah, bh, acc[nf], 0, 0, 0);
                acc[nf] = __builtin_amdgcn_mfma_f32_16x16x32_bf16(ah, bl, acc[nf], 0, 0, 0);
                acc[nf] = __builtin_amdgcn_mfma_f32_16x16x32_bf16(al, bh, acc[nf], 0, 0, 0);
            }
        }
        // extract rows 0..3 (held by quad 0, reg i = row i) + add Zx
        if (quad == 0) {
#pragma unroll
            for (int nf = 0; nf < 8; nf++) {
                int col = wn + nf * 16 + l16;
#pragma unroll
                for (int i = 0; i < 4; i++)
                    zb[i][col] = acc[nf][i] + Zx[((size_t)(r0 + i) * TT + t) * 512 + col];
            }
        }
        __syncthreads();

        // ---- phase 2: LN stats per (row, gate) ----
        {
            int grp = tid >> 4;
            int row = grp >> 2, gate = grp & 3;
            int l = tid & 15;
            float s = 0.f, ss = 0.f;
#pragma unroll
            for (int j = 0; j < 8; j++) {
                float v = zb[row][gate * 128 + l + j * 16];
                s += v; ss += v * v;
            }
#pragma unroll
            for (int off = 1; off < 16; off <<= 1) {
                s += __shfl_xor(s, off);
                ss += __shfl_xor(ss, off);
            }
            if (l == 0) {
                float m_ = s * (1.f / 128.f);
                mu[row][gate] = m_;
                rs[row][gate] = rsqrtf(ss * (1.f / 128.f) - m_ * m_ + 1e-12f);
            }
        }
        __syncthreads();

        // ---- phase 3: gates + cell update ----
        float ogate[2];
#pragma unroll
        for (int ii = 0; ii < 2; ii++) {
            int idx = tid + ii * 256;
            int row = idx >> 7, col = idx & 127;
            float i_g = (zb[row][col]       - mu[row][0]) * rs[row][0] * g[0 * 128 + col] + bb[0 * 128 + col];
            float j_g = (zb[row][128 + col] - mu[row][1]) * rs[row][1] * g[1 * 128 + col] + bb[1 * 128 + col];
            float f_g = (zb[row][256 + col] - mu[row][2]) * rs[row][2] * g[2 * 128 + col] + bb[2 * 128 + col];
            float o_g = (zb[row][384 + col] - mu[row][3]) * rs[row][3] * g[3 * 128 + col] + bb[3 * 128 + col];
            float nc = cs[row][col] * sigf(f_g + 1.f) + sigf(i_g) * fmaxf(j_g, 0.f);
            cs[row][col] = nc;
            ogate[ii] = o_g;
        }
        __syncthreads();

        // ---- phase 4: LN stats over new c ----
        {
            int ww = tid >> 6, l = tid & 63;
            float v0 = cs[ww][l], v1 = cs[ww][l + 64];
            float s = v0 + v1, ss = v0 * v0 + v1 * v1;
#pragma unroll
            for (int off = 1; off < 64; off <<= 1) {
                s += __shfl_xor(s, off);
                ss += __shfl_xor(ss, off);
            }
            if (l == 0) {
                float m_ = s * (1.f / 128.f);
                cmu[ww] = m_;
                crs[ww] = rsqrtf(ss * (1.f / 128.f) - m_ * m_ + 1e-12f);
            }
        }
        __syncthreads();

        // ---- phase 5: h = relu(LN(c)) * sigmoid(o); store h as bf16 hi/lo ----
#pragma unroll
        for (int ii = 0; ii < 2; ii++) {
            int idx = tid + ii * 256;
            int row = idx >> 7, col = idx & 127;
            float lnc = (cs[row][col] - cmu[row]) * crs[row] * g[4 * 128 + col] + bb[4 * 128 + col];
            float hv = fmaxf(lnc, 0.f) * sigf(ogate[ii]);
            ushort hh = f2bf(hv);
            hbh[row][col] = hh;
            hbl[row][col] = f2bf(hv - bf2f(hh));
            obuf[((size_t)(r0 + row) * TT + t) * 128 + col] = hv;
        }
        __syncthreads();
    }
}

// Attention (unchanged).
__global__ __launch_bounds__(256) void attn_kernel(
    const float* __restrict__ o1, const float* __restrict__ o2,
    const float* __restrict__ v1, const float* __restrict__ v2,
    const float* __restrict__ Wo1, const float* __restrict__ Wo2,
    const float* __restrict__ bo1, const float* __restrict__ bo2,
    float* __restrict__ acat) {
    int lstm = blockIdx.x >> 7;
    int b = blockIdx.x & 127;
    const float* o  = (lstm ? o2 : o1) + (size_t)b * TT * 128;
    const float* v  = lstm ? v2 : v1;
    const float* Wo = lstm ? Wo2 : Wo1;
    const float* bo = lstm ? bo2 : bo1;
    __shared__ float sc[64];
    __shared__ float ctx[128];
    int tid = threadIdx.x;
    if (tid < TT) {
        float s = 0.f;
        for (int h = 0; h < 128; h++) s = fmaf(o[tid * 128 + h], v[h], s);
        sc[tid] = s;
    }
    __syncthreads();
    if (tid < 64) {
        float x = (tid < TT) ? sc[tid] : -1e30f;
        float m = x;
#pragma unroll
        for (int off = 1; off < 64; off <<= 1) m = fmaxf(m, __shfl_xor(m, off));
        float e = (tid < TT) ? expf(x - m) : 0.f;
        float s = e;
#pragma unroll
        for (int off = 1; off < 64; off <<= 1) s += __shfl_xor(s, off);
        if (tid < TT) sc[tid] = e / s;
    }
    __syncthreads();
    if (tid < 128) {
        float s = 0.f;
        for (int t = 0; t < TT; t++) s = fmaf(sc[t], o[t * 128 + tid], s);
        ctx[tid] = s;
    }
    __syncthreads();
#pragma unroll
    for (int j = 0; j < 2; j++) {
        int n = tid * 2 + j;
        float s = bo[n];
        for (int h = 0; h < 128; h++) s = fmaf(ctx[h], Wo[h * 512 + n], s);
        acat[(size_t)b * 1024 + lstm * 512 + n] = fmaxf(s, 0.f);
    }
}

// Final MLP (unchanged).
__global__ __launch_bounds__(256) void final_kernel(
    const float* __restrict__ acat, const float* __restrict__ Wh,
    const float* __restrict__ bh, const float* __restrict__ Wout,
    const float* __restrict__ bout, float* __restrict__ out) {
    int b = blockIdx.x;
    __shared__ float ain[1024];
    __shared__ float hid[512];
    __shared__ float red[4];
    int tid = threadIdx.x;
    for (int i = tid; i < 1024; i += 256) ain[i] = acat[(size_t)b * 1024 + i];
    __syncthreads();
#pragma unroll
    for (int j = 0; j < 2; j++) {
        int n = tid * 2 + j;
        float s = bh[n];
        for (int k = 0; k < 1024; k++) s = fmaf(ain[k], Wh[(size_t)k * 512 + n], s);
        hid[n] = fmaxf(s, 0.f);
    }
    __syncthreads();
    for (int j = 0; j < 2; j++) {
        float p = 0.f;
        for (int k = tid; k < 512; k += 256) p = fmaf(hid[k], Wout[k * 2 + j], p);
#pragma unroll
        for (int off = 1; off < 64; off <<= 1) p += __shfl_xor(p, off);
        if ((tid & 63) == 0) red[tid >> 6] = p;
        __syncthreads();
        if (tid == 0) out[b * 2 + j] = red[0] + red[1] + red[2] + red[3] + bout[j];
        __syncthreads();
    }
}

extern "C" void kernel_launch(void* const* d_in, const int* in_sizes, int n_in,
                              void* d_out, int out_size, void* d_ws, size_t ws_size,
                              hipStream_t stream) {
    const float* x1      = (const float*)d_in[0];
    const float* x2      = (const float*)d_in[1];
    const float* embed1  = (const float*)d_in[2];
    const float* embed2  = (const float*)d_in[3];
    const float* W_lstm1 = (const float*)d_in[4];
    const float* W_lstm2 = (const float*)d_in[5];
    const float* lng1    = (const float*)d_in[6];
    const float* lnb1    = (const float*)d_in[7];
    const float* lng2    = (const float*)d_in[8];
    const float* lnb2    = (const float*)d_in[9];
    const float* attn_v1 = (const float*)d_in[10];
    const float* attn_Wo1= (const float*)d_in[11];
    const float* attn_bo1= (const float*)d_in[12];
    const float* attn_v2 = (const float*)d_in[13];
    const float* attn_Wo2= (const float*)d_in[14];
    const float* attn_bo2= (const float*)d_in[15];
    const float* W_h     = (const float*)d_in[16];
    const float* b_h     = (const float*)d_in[17];
    const float* W_out   = (const float*)d_in[18];
    const float* b_out   = (const float*)d_in[19];
    float* out = (float*)d_out;

    // Workspace layout
    ushort* EWt_hi = (ushort*)d_ws;                      // 512*8192 bf16 (8 MB)
    ushort* EWt_lo = EWt_hi + (size_t)512 * 8192;        // 8 MB
    float* Zx1 = (float*)(EWt_lo + (size_t)512 * 8192);  // 5888*512 f32 (12 MB)
    float* Zx2 = Zx1 + 3014656;
    float* o1  = Zx2 + 3014656;                          // 128*46*128 f32
    float* o2  = o1 + 753664;
    float* acat = o2 + 753664;                           // 128*1024 f32
    ushort* Wht_hi = (ushort*)(acat + 131072);           // 2*512*128 bf16
    ushort* Wht_lo = Wht_hi + 2 * 512 * 128;
    // total ~45.8 MiB

    hipMemsetAsync(Zx1, 0, (size_t)3014656 * 4, stream);
    hipMemsetAsync(Zx2, 0, (size_t)3014656 * 4, stream);
    wht_prep<<<32, 256, 0, stream>>>(W_lstm1, W_lstm2, Wht_hi, Wht_lo);

    // Branch 1
    ew_kernel<<<dim3(64, 4), 512, 0, stream>>>(embed1, W_lstm1, EWt_hi, EWt_lo);
    zx_kernel<<<dim3(46, 2, 8), 256, 0, stream>>>(x1, EWt_hi, EWt_lo, Zx1);
    // Branch 2 (reuses EWt buffers)
    ew_kernel<<<dim3(64, 4), 512, 0, stream>>>(embed2, W_lstm2, EWt_hi, EWt_lo);
    zx_kernel<<<dim3(46, 2, 8), 256, 0, stream>>>(x2, EWt_hi, EWt_lo, Zx2);

    lstm_kernel<<<64, 256, 0, stream>>>(Zx1, Zx2, Wht_hi, Wht_lo,
                                        lng1, lnb1, lng2, lnb2, o1, o2);
    attn_kernel<<<256, 256, 0, stream>>>(o1, o2, attn_v1, attn_v2,
                                         attn_Wo1, attn_Wo2, attn_bo1, attn_bo2, acat);
    final_kernel<<<128, 256, 0, stream>>>(acat, W_h, b_h, W_out, b_out, out);
}